// Round 6
// baseline (109.546 us; speedup 1.0000x reference)
//
#include <hip/hip_runtime.h>
#include <cstdint>
#include <cstddef>

#define NQ 900
#define NC 91
#define NFLAT (NQ * NC)        // 81900
#define NF4 (NFLAT / 4)        // 20475
#define BS 8
#define PRE_TOPK 10000
#define TOPK 100
#define IOU_THR 0.7f
#define NT 1024
#define NWAVES (NT / 64)
#define HB 2048                // bins on z over [-4,4)
#define BINGUESS 1280          // bin_of(1.0): pool holds z >= 1.0 (~13K of 81.9K)
#define WCAP 960               // per-wave pool segment capacity (exp 813, +5.6 sigma)
#define POOLSZ (NWAVES * WCAP) // 15360
#define TCAP 1088              // sorted-top capacity
#define E2CAND 1024            // target sorted-prefix length
#define BBCAP 1024             // crossing-bin capacity (exp ~64)
#define ELIG 0x40000000
#define LENMASK 0x3FFFFFFF

// sigmoid monotone => order on raw logit z == order on prob.
__device__ __forceinline__ unsigned int mono_u(float z) {
    unsigned int b = __float_as_uint(z);
    return b ^ ((unsigned int)((int)b >> 31) | 0x80000000u);
}
__device__ __forceinline__ float inv_mono(unsigned int u) {
    unsigned int b = (u & 0x80000000u) ? (u ^ 0x80000000u) : ~u;
    return __uint_as_float(b);
}
// 49-bit distinct key == lax.top_k order (score desc, idx asc)
__device__ __forceinline__ unsigned long long make_key(unsigned int u, int i) {
    return ((unsigned long long)u << 17) | (unsigned long long)(131071 - i);
}
__device__ __forceinline__ int bin_of(float z) {
    float t = (z + 4.0f) * 256.0f;
    t = fmaxf(t, 0.0f); t = fminf(t, 2047.0f);
    return (int)t;
}
__device__ __forceinline__ int bin_of_key(unsigned long long k) {
    return bin_of(inv_mono((unsigned int)(k >> 17)));
}

extern "C" __global__ __launch_bounds__(NT)
void NMSPostProcess_70463233458602_kernel(const float* __restrict__ logits,
                                          const float* __restrict__ pboxes,
                                          const float* __restrict__ tsizes,
                                          float* __restrict__ out) {
    __shared__ unsigned long long sPool[POOLSZ]; // 120 KB: per-wave segments of keys
    __shared__ unsigned long long sTop[TCAP];    // 8.5 KB: sorted top prefix
    __shared__ unsigned long long sBinB[BBCAP];  // 8 KB: crossing bin (then sorted)
    __shared__ int sHist[HB];                    // raw counts (+ELIG bit later)
    __shared__ int sScan[HB];                    // exclusive-above; scatter cursors
    __shared__ unsigned long long sLazy[64];
    __shared__ float sKx1[TOPK], sKy1[TOPK], sKx2[TOPK], sKy2[TOPK], sKa[TOPK];
    __shared__ float sFirst[6];
    __shared__ float sRedF[NWAVES];
    __shared__ int sWTot[NWAVES], sWSuf[NWAVES], sWCnt[NWAVES];
    __shared__ int sFlag, sB, sRem, sAbove, sKept, sBinBCnt, sPos, sE2, sLin;
    __shared__ unsigned long long sT;
    __shared__ float sBmax;

    const int b = blockIdx.x;
    const int tid = threadIdx.x;
    const int wid = tid >> 6, lane = tid & 63;
    const float* lg = logits + (size_t)b * NFLAT;
    const float* bx = pboxes + (size_t)b * NQ * 4;
    const float img_h = tsizes[b * 2 + 0], img_w = tsizes[b * 2 + 1];
    const unsigned long long laneLT = (1ULL << lane) - 1ULL;
    const int wBase = wid * WCAP;

    sHist[tid] = 0; sHist[tid + NT] = 0;
    if (tid == 0) { sFlag = 0; sBinBCnt = 0; sPos = 0; sLin = 0; }
    __syncthreads();

    // ---- pass A: histogram on z + per-wave pool append (bin >= BINGUESS) ----
    {
        int wCnt = 0;
        #pragma unroll 2
        for (int j = tid; j < NF4; j += NT) {
            const float4 v = ((const float4*)lg)[j];
            const float zv[4] = { v.x, v.y, v.z, v.w };
            #pragma unroll
            for (int q = 0; q < 4; ++q) {
                const int bk = bin_of(zv[q]);
                atomicAdd(&sHist[bk], 1);
                const bool cand = bk >= BINGUESS;
                const unsigned long long mask = __ballot(cand);
                if (cand) {
                    const int off = wCnt + __popcll(mask & laneLT);
                    if (off < WCAP) sPool[wBase + off] = make_key(mono_u(zv[q]), 4 * j + q);
                }
                wCnt += __popcll(mask);
            }
        }
        if (lane == 0) {
            sWCnt[wid] = wCnt < WCAP ? wCnt : WCAP;
            if (wCnt > WCAP) atomicOr(&sFlag, 1);   // pool overflow -> fallback
        }
    }
    __syncthreads();

    // ---- shfl-based hierarchical suffix scan over 2048 bins ----
    {
        const int b0 = 2 * tid, b1 = 2 * tid + 1;
        const int h0 = sHist[b0], h1 = sHist[b1];
        const int s = h0 + h1;
        int v = s;
        #pragma unroll
        for (int off = 1; off < 64; off <<= 1) {
            const int o = __shfl(v, lane + off, 64);
            if (lane + off < 64) v += o;
        }
        if (lane == 0) sWTot[wid] = v;
        __syncthreads();
        if (wid == 0) {
            int t = (lane < NWAVES) ? sWTot[lane] : 0;
            #pragma unroll
            for (int off = 1; off < NWAVES; off <<= 1) {
                const int o = __shfl(t, lane + off, 64);
                if (lane + off < NWAVES) t += o;
            }
            if (lane < NWAVES) sWSuf[lane] = t;
        }
        __syncthreads();
        const int afterWave = sWSuf[wid] - sWTot[wid];
        const int afterPairs = (v - s) + afterWave;
        const int si1 = h1 + afterPairs;
        const int si0 = h0 + si1;
        sScan[b0] = si1;
        sScan[b1] = afterPairs;
        if (si0 >= PRE_TOPK && si1 < PRE_TOPK)        { sB = b0; sAbove = si1;        sRem = PRE_TOPK - si1; }
        if (si1 >= PRE_TOPK && afterPairs < PRE_TOPK) { sB = b1; sAbove = afterPairs; sRem = PRE_TOPK - afterPairs; }
    }
    __syncthreads();
    if (tid == 0 && sB < BINGUESS) sFlag = 1;   // pool doesn't cover top-10000
    __syncthreads();
    const int B = sB, above = sAbove, rem = sRem;
    int bad = sFlag;

    if (!bad) {
        // ---- collect crossing bin from own pool segment (ballot append) ----
        const int cnt = sWCnt[wid];
        const int lim = (cnt + 63) & ~63;
        for (int off = lane; off < lim; off += 64) {
            const bool have = off < cnt;
            const unsigned long long k = have ? sPool[wBase + off] : 0ULL;
            const bool isB = have && (bin_of_key(k) == B);
            const unsigned long long mask = __ballot(isB);
            const int n = __popcll(mask);
            int pos = 0;
            if (lane == 0 && n) pos = atomicAdd(&sBinBCnt, n);
            pos = __shfl(pos, 0, 64);
            if (isB) {
                const int p2 = pos + __popcll(mask & laneLT);
                if (p2 < BBCAP) sBinB[p2] = k;
            }
        }
        __syncthreads();
        if (tid == 0 && sBinBCnt > BBCAP) sFlag = 1;
        __syncthreads();
        bad = sFlag;
    }

    if (!bad) {
        // ---- exact sort of crossing bin (rank-select); T = 10000th key ----
        const int cntB = sBinBCnt;
        unsigned long long kk = 0ULL; int r = -1;
        if (tid < cntB) {
            kk = sBinB[tid]; r = 0;
            for (int q = 0; q < cntB; ++q) r += (sBinB[q] > kk) ? 1 : 0;
        }
        __syncthreads();
        if (r >= 0) sBinB[r] = kk;
        __syncthreads();
        if (tid == 0) sT = sBinB[rem - 1];
        __syncthreads();
        const unsigned long long T = sT;

        // ---- bmax over exact top-10000 (pool membership: key >= T) ----
        float lmax = -3.4e38f;
        const int cnt = sWCnt[wid];
        for (int off = lane; off < cnt; off += 64) {
            const unsigned long long k = sPool[wBase + off];
            if (k >= T) {
                const int i = 131071 - (int)(k & 0x1FFFFULL);
                const int bi = i / NC;
                const float4 bb = ((const float4*)bx)[bi];
                const float x1 = (bb.x - 0.5f * bb.z) * img_w;
                const float y1 = (bb.y - 0.5f * bb.w) * img_h;
                const float x2 = (bb.x + 0.5f * bb.z) * img_w;
                const float y2 = (bb.y + 0.5f * bb.w) * img_h;
                lmax = fmaxf(lmax, fmaxf(fmaxf(x1, y1), fmaxf(x2, y2)));
            }
        }
        for (int off = 32; off >= 1; off >>= 1)
            lmax = fmaxf(lmax, __shfl_xor(lmax, off, 64));
        if (lane == 0) sRedF[wid] = lmax;
        if (tid == 0) sE2 = above < E2CAND ? above : E2CAND;
        __syncthreads();
        if (tid == 0) {
            float mm = sRedF[0];
            for (int k2 = 1; k2 < NWAVES; ++k2) mm = fmaxf(mm, sRedF[k2]);
            sBmax = mm;
        }
        // ---- sorted-prefix extent E2 (contiguous coverage from 0) ----
        {
            const int bks[2] = { 2 * tid, 2 * tid + 1 };
            #pragma unroll
            for (int q = 0; q < 2; ++q) {
                const int bk = bks[q];
                if (bk > B && sHist[bk] > 0 && sScan[bk] < E2CAND &&
                    sScan[bk] + sHist[bk] > TCAP)
                    atomicMin(&sE2, sScan[bk]);
            }
        }
        __syncthreads();
        const int E2 = sE2;
        // mark eligible bins (start < E2 implies end <= TCAP)
        {
            const int bks[2] = { 2 * tid, 2 * tid + 1 };
            #pragma unroll
            for (int q = 0; q < 2; ++q) {
                const int bk = bks[q];
                if (bk > B && sHist[bk] > 0 && sScan[bk] < E2) sHist[bk] |= ELIG;
            }
        }
        __syncthreads();
        // ---- scatter eligible pool keys into sTop (cursor = sScan atomic) ----
        for (int off = lane; off < cnt; off += 64) {
            const unsigned long long k = sPool[wBase + off];
            const int bk = bin_of_key(k);
            if (sHist[bk] & ELIG) {
                const int pos = atomicAdd(&sScan[bk], 1);
                if (pos < TCAP) sTop[pos] = k;
            }
        }
        __syncthreads();
        // ---- in-bin rank of sTop positions [0, X) (X = contiguous coverage) ----
        {
            unsigned long long stash[2]; int spp[2]; int ns = 0;
            for (int p = tid; p < TCAP; p += NT) {
                // position p written iff some eligible bin covers it; detect via key
                // only ranks positions inside eligible bins' ranges:
                // iterate instead over both owned bins' elements? simpler: check
                // coverage: p < E2 guaranteed; also crossing-into-[E2,TCAP) parts.
                if (p >= E2) break;   // NMS only reads < E2; ranks within-bin stay consistent
                const unsigned long long k = sTop[p];
                const int bk = bin_of_key(k);
                const int len = sHist[bk] & LENMASK;
                const int s0 = sScan[bk] - len;      // post-scatter cursor - len = start
                int r2 = 0;
                for (int q = 0; q < len; ++q) r2 += (sTop[s0 + q] > k) ? 1 : 0;
                if (ns < 2) { stash[ns] = k; spp[ns] = s0 + r2; ++ns; }
            }
            __syncthreads();
            for (int q = 0; q < ns; ++q) sTop[spp[q]] = stash[q];
        }
        __syncthreads();
    }

    __syncthreads();
    bad = sFlag;
    if (bad) {
        // ======== fallback (never taken for sane inputs; fully exact) ========
        unsigned long long lo = 0, hi = (1ULL << 49) - 1;
        while (lo < hi) {
            const unsigned long long mid = lo + ((hi - lo + 1) >> 1);
            int c = 0;
            for (int j = tid; j < NF4; j += NT) {
                const float4 v = ((const float4*)lg)[j];
                const float zv[4] = { v.x, v.y, v.z, v.w };
                #pragma unroll
                for (int q = 0; q < 4; ++q)
                    c += (make_key(mono_u(zv[q]), 4 * j + q) >= mid) ? 1 : 0;
            }
            for (int off = 32; off >= 1; off >>= 1) c += __shfl_xor(c, off, 64);
            if (lane == 0) sWTot[wid] = c;
            __syncthreads();
            if (tid == 0) {
                int a = 0;
                for (int w = 0; w < NWAVES; ++w) a += sWTot[w];
                sPos = a;
            }
            __syncthreads();
            if (sPos >= PRE_TOPK) lo = mid; else hi = mid - 1;
            __syncthreads();
        }
        if (tid == 0) sPos = 0;
        __syncthreads();
        for (int j = tid; j < NF4; j += NT) {
            const float4 v = ((const float4*)lg)[j];
            const float zv[4] = { v.x, v.y, v.z, v.w };
            #pragma unroll
            for (int q = 0; q < 4; ++q) {
                const unsigned long long k = make_key(mono_u(zv[q]), 4 * j + q);
                const bool cand = k >= lo;           // exactly 10000 (keys distinct)
                const unsigned long long mask = __ballot(cand);
                int pos = 0;
                if (lane == 0 && mask) pos = atomicAdd(&sPos, __popcll(mask));
                pos = __shfl(pos, 0, 64);
                if (cand) sPool[pos + __popcll(mask & laneLT)] = k;
            }
        }
        __syncthreads();
        {   // full rank sort of 10000 (slow, correct)
            unsigned long long stash[10]; int spp[10]; int ns = 0;
            for (int p = tid; p < PRE_TOPK; p += NT) {
                const unsigned long long k = sPool[p];
                int r = 0;
                for (int q = 0; q < PRE_TOPK; ++q) r += (sPool[q] > k) ? 1 : 0;
                if (ns < 10) { stash[ns] = k; spp[ns] = r; ++ns; }
            }
            __syncthreads();
            for (int q = 0; q < ns; ++q) sPool[spp[q]] = stash[q];
        }
        __syncthreads();
        float lmax = -3.4e38f;
        for (int p = tid; p < PRE_TOPK; p += NT) {
            const int i = 131071 - (int)(sPool[p] & 0x1FFFFULL);
            const int bi = i / NC;
            const float4 bb = ((const float4*)bx)[bi];
            const float x1 = (bb.x - 0.5f * bb.z) * img_w;
            const float y1 = (bb.y - 0.5f * bb.w) * img_h;
            const float x2 = (bb.x + 0.5f * bb.z) * img_w;
            const float y2 = (bb.y + 0.5f * bb.w) * img_h;
            lmax = fmaxf(lmax, fmaxf(fmaxf(x1, y1), fmaxf(x2, y2)));
        }
        for (int off = 32; off >= 1; off >>= 1)
            lmax = fmaxf(lmax, __shfl_xor(lmax, off, 64));
        if (lane == 0) sRedF[wid] = lmax;
        __syncthreads();
        if (tid == 0) {
            float mm = sRedF[0];
            for (int k2 = 1; k2 < NWAVES; ++k2) mm = fmaxf(mm, sRedF[k2]);
            sBmax = mm;
            sLin = 1;
        }
        __syncthreads();
    }

    const float offc = sBmax + 1.0f;   // labels * (boxes.max() + 1)
    const int E2 = sE2;
    const int lin = sLin;

    // ---- sorted-scan NMS (wave 0) ----
    if (wid == 0) {
        int kept = 0;
        unsigned long long lazyPrev = ~0ULL;
        int lazyInit = 0;
        for (int base = 0; base < PRE_TOPK && kept < TOPK; base += 64) {
            if (!lin) {   // lazy extraction for positions [E2, above) in this chunk
                const int lo2 = base > E2 ? base : E2;
                const int hi2 = (base + 64 < above) ? base + 64 : above;
                if (lo2 < hi2) {
                    if (!lazyInit) {
                        lazyPrev = (E2 > 0) ? sTop[E2 - 1] : ~0ULL;
                        lazyInit = 1;
                    }
                    for (int p = lo2; p < hi2; ++p) {
                        unsigned long long best = 0ULL;
                        for (int w2 = 0; w2 < NWAVES; ++w2) {
                            const int c2 = sWCnt[w2]; const int b2 = w2 * WCAP;
                            for (int off = lane; off < c2; off += 64) {
                                const unsigned long long k2 = sPool[b2 + off];
                                if (k2 < lazyPrev && k2 > best) best = k2;
                            }
                        }
                        for (int off = 32; off >= 1; off >>= 1) {
                            const unsigned long long o = __shfl_xor(best, off, 64);
                            best = o > best ? o : best;
                        }
                        if (lane == 0) sLazy[p - base] = best;
                        lazyPrev = best;
                    }
                }
            }
            const int c = base + lane;
            const bool valid = c < PRE_TOPK;
            unsigned long long k = 0ULL;
            if (valid) {
                if (lin)            k = sPool[c];
                else if (c < E2)    k = sTop[c];
                else if (c >= above) k = sBinB[c - above];
                else                k = sLazy[c - base];
            }
            const int i = valid ? (131071 - (int)(k & 0x1FFFFULL)) : 0;
            const int bi = i / NC, l = i - bi * NC;
            const float4 bb = ((const float4*)bx)[bi];
            const float bx1 = (bb.x - 0.5f * bb.z) * img_w;
            const float by1 = (bb.y - 0.5f * bb.w) * img_h;
            const float bx2 = (bb.x + 0.5f * bb.z) * img_w;
            const float by2 = (bb.y + 0.5f * bb.w) * img_h;
            const float o = (float)l * offc;
            const float ox1 = bx1 + o, oy1 = by1 + o, ox2 = bx2 + o, oy2 = by2 + o;
            const float ar = (ox2 - ox1) * (oy2 - oy1);
            bool alive = valid;
            for (int jj = 0; jj < kept; ++jj) {
                float iw = fminf(sKx2[jj], ox2) - fmaxf(sKx1[jj], ox1);
                float ih = fminf(sKy2[jj], oy2) - fmaxf(sKy1[jj], oy1);
                iw = fmaxf(iw, 0.f); ih = fmaxf(ih, 0.f);
                const float inter = iw * ih;
                if (inter > IOU_THR * (sKa[jj] + ar - inter)) alive = false;
            }
            unsigned long long mask = __ballot(alive);
            while (mask != 0ULL && kept < TOPK) {
                const int s = __ffsll((unsigned long long)mask) - 1;
                const float px1 = __shfl(ox1, s, 64);
                const float py1 = __shfl(oy1, s, 64);
                const float px2 = __shfl(ox2, s, 64);
                const float py2 = __shfl(oy2, s, 64);
                const float pa  = __shfl(ar,  s, 64);
                if (lane == s) {
                    sKx1[kept] = ox1; sKy1[kept] = oy1; sKx2[kept] = ox2; sKy2[kept] = oy2; sKa[kept] = ar;
                    const int oi = b * TOPK + kept;
                    const float z = inv_mono((unsigned int)(k >> 17));
                    const float sc = 1.0f / (1.0f + expf(-z));
                    out[oi] = sc;
                    out[BS * TOPK + oi] = (float)l;
                    out[2 * BS * TOPK + oi * 4 + 0] = bx1;
                    out[2 * BS * TOPK + oi * 4 + 1] = by1;
                    out[2 * BS * TOPK + oi * 4 + 2] = bx2;
                    out[2 * BS * TOPK + oi * 4 + 3] = by2;
                    if (kept == 0) { sFirst[0] = sc; sFirst[1] = (float)l;
                                     sFirst[2] = bx1; sFirst[3] = by1;
                                     sFirst[4] = bx2; sFirst[5] = by2; }
                }
                ++kept;
                if (alive) {
                    float iw = fminf(px2, ox2) - fmaxf(px1, ox1);
                    float ih = fminf(py2, oy2) - fmaxf(py1, oy1);
                    iw = fmaxf(iw, 0.f); ih = fmaxf(ih, 0.f);
                    const float inter = iw * ih;
                    if (inter > IOU_THR * (pa + ar - inter)) alive = false;
                }
                mask = __ballot(alive);
            }
        }
        if (lane == 0) sKept = kept;
    }
    __syncthreads();
    // exhaustion: ref's argmax over all -inf -> index 0 -> replicate row 0
    for (int t = sKept + tid; t < TOPK; t += NT) {
        const int oi = b * TOPK + t;
        out[oi] = sFirst[0];
        out[BS * TOPK + oi] = sFirst[1];
        out[2 * BS * TOPK + oi * 4 + 0] = sFirst[2];
        out[2 * BS * TOPK + oi * 4 + 1] = sFirst[3];
        out[2 * BS * TOPK + oi * 4 + 2] = sFirst[4];
        out[2 * BS * TOPK + oi * 4 + 3] = sFirst[5];
    }
}

extern "C" void kernel_launch(void* const* d_in, const int* in_sizes, int n_in,
                              void* d_out, int out_size, void* d_ws, size_t ws_size,
                              hipStream_t stream) {
    const float* logits = (const float*)d_in[0];   // (8, 900, 91) fp32
    const float* pboxes = (const float*)d_in[1];   // (8, 900, 4) fp32
    const float* ts     = (const float*)d_in[2];   // (8, 2) fp32
    hipLaunchKernelGGL(NMSPostProcess_70463233458602_kernel,
                       dim3(BS), dim3(NT), 0, stream,
                       logits, pboxes, ts, (float*)d_out);
}